// Round 10
// baseline (256.295 us; speedup 1.0000x reference)
//
#include <hip/hip_runtime.h>
#include <hip/hip_bf16.h>

#define BN    4
#define NN    2048
#define INF   128
#define HH    8
#define HD    16
#define ALPHA 0.2f
#define DECAY 0.1f

// exp2 folding: staged w2 = log2e * exp(-DECAY*(ct-t)) = exp2(fma(DLOG2E,t,c0)),
// c0 = -DLOG2E*ct + log2(log2e); inner p = exp2(sc * w2)  (saves 1 mul/elem).
#define DLOG2E 0.14426950408889634f   // DECAY * log2(e)
#define LLOG2E 0.5287663729448977f    // log2(log2(e))

typedef __attribute__((ext_vector_type(8))) short short8;
typedef __attribute__((ext_vector_type(4))) float float4v;

__device__ __forceinline__ float bf2f(unsigned short u) {
    return __uint_as_float(((unsigned)u) << 16);
}

// ---------------- Kernel 0: zero ct + transpose W for coalesced proj -------
// Wt[i][h*16+d] = W[h][i][d]; 64 KB total, 1 block. Also ct = 0.
__global__ void k_prep(const float* __restrict__ W, float* __restrict__ Wt,
                       unsigned* __restrict__ ct) {
    int t = threadIdx.x;  // 256
    if (t == 0) *ct = 0u;
    for (int e = t; e < HH * INF * HD; e += 256) {
        int h = e >> 11;          // /(128*16)
        int i = (e >> 4) & 127;
        int d = e & 15;
        Wt[i * 128 + h * 16 + d] = W[e];
    }
}

// ---------------- Kernel 1: fused [max over tm] + [proj h_t/es/ed] ---------
__launch_bounds__(256, 8)
__global__ void k_setup(const float* __restrict__ x,
                        const float* __restrict__ Wt,
                        const float* __restrict__ a,
                        const float* __restrict__ tm,
                        unsigned* __restrict__ ct,
                        __hip_bfloat16* __restrict__ h_t,
                        float* __restrict__ es, float* __restrict__ ed) {
    if (blockIdx.x < 1024) {
        // ct = max(tm); values >= 0 so u32-compare == f32-compare
        const uint4* p = (const uint4*)tm;
        const int nvec = BN * NN * NN / 4;
        int idx = blockIdx.x * 256 + threadIdx.x;
        const int stride = 1024 * 256;
        unsigned m = 0u;
        for (int i = idx; i < nvec; i += stride) {
            uint4 v = p[i];
            m = max(m, v.x); m = max(m, v.y); m = max(m, v.z); m = max(m, v.w);
        }
        float fm = __uint_as_float(m);
        #pragma unroll
        for (int o = 32; o >= 1; o >>= 1) fm = fmaxf(fm, __shfl_xor(fm, o));
        __shared__ float sm[4];
        if ((threadIdx.x & 63) == 0) sm[threadIdx.x >> 6] = fm;
        __syncthreads();
        if (threadIdx.x == 0) {
            float mm = fmaxf(fmaxf(sm[0], sm[1]), fmaxf(sm[2], sm[3]));
            atomicMax(ct, __float_as_uint(mm));
        }
    } else {
        // proj: thread tt = h*16+d reads Wt[i*128+tt] -> fully coalesced
        int bid = blockIdx.x - 1024;          // 0..4095
        int sub = threadIdx.x >> 7;
        int tt  = threadIdx.x & 127;          // = h*16 + d
        int nn  = bid * 2 + sub;              // b*NN+n
        __shared__ float xs[2][INF];
        xs[sub][tt] = x[(size_t)nn * INF + tt];
        __syncthreads();
        int h = tt >> 4, d = tt & 15;
        float acc = 0.f;
        #pragma unroll 16
        for (int i = 0; i < INF; i++) acc += xs[sub][i] * Wt[i * 128 + tt];
        int b = nn >> 11, n = nn & 2047;
        h_t[((size_t)((b * HH + h) * HD + d)) * NN + n] = __float2bfloat16(acc);
        float s  = acc * a[h * 2 * HD + d];
        float dd = acc * a[h * 2 * HD + HD + d];
        #pragma unroll
        for (int o = 8; o >= 1; o >>= 1) { s += __shfl_xor(s, o); dd += __shfl_xor(dd, o); }
        if (d == 0) {
            es[(b * HH + h) * NN + n] = s;
            ed[(b * HH + h) * NN + n] = dd;
        }
    }
}

// ---------------- Kernel 2: fused scores + softmax + PV (MFMA) -------------
// EXACT r5 structure (best measured: 75.3 us) -- 512 thr = 8 waves = 8 heads,
// grid 512, full j-range R=16, single-buffered padded tile tws[16][132],
// 2 barriers/round with register prefetch of next round's tm/adj, ed from
// global, scalar bf16 convert, shuffle row-sum. Only delta vs r5: exp2-fold
// (w2 pre-scaled by log2e in staging; inner saves one v_mul per element).
// r6-r9 lesson: double-buffer/1-barrier, ones-MFMA, perm-pack, 4-wave
// blocks, higher occupancy ALL regressed (78/92/86/98 vs 75).
__launch_bounds__(512, 4)
__global__ void k_attn(const int* __restrict__ adj,
                       const float* __restrict__ tm,
                       const __hip_bfloat16* __restrict__ h_t,
                       const float* __restrict__ es, const float* __restrict__ ed,
                       const unsigned* __restrict__ ctp,
                       float* __restrict__ out) {
    int t    = threadIdx.x;
    int w    = t >> 6;          // head
    int lane = t & 63;
    int q    = lane >> 4;       // quad 0..3
    int im   = lane & 15;       // i within tile / d for B-frag
    int b    = blockIdx.x >> 7;
    int i0   = (blockIdx.x & 127) << 4;
    int i    = i0 + im;
    const int R = 16;           // 16 rounds x 128 j

    __shared__ float tws[16][132];   // padded rows: 16B-aligned, as r5

    float ctv = __uint_as_float(*ctp);
    float c0  = fmaf(-DLOG2E, ctv, LLOG2E);
    float es_i = es[(b * HH + w) * NN + i];

    const float* ed_p = ed + (size_t)(b * HH + w) * NN + q * 8;
    const __hip_bfloat16* ht_p = h_t + ((size_t)((b * HH + w) * HD + im)) * NN + q * 8;

    // staging map: 512 threads x 4 elements = 16 rows x 128 cols
    int srow = t >> 5;            // 0..15
    int scol = (t & 31) << 2;     // 0,4,...,124
    const int*   adj_s = adj + ((size_t)(b * NN + i0 + srow)) * NN + scol;
    const float* tm_s  = tm  + ((size_t)(b * NN + i0 + srow)) * NN + scol;

    float4v acc = {0.f, 0.f, 0.f, 0.f};
    float lsum = 0.f;

    // prefetch round 0
    int4   pa = *(const int4*)(adj_s);
    float4 pt = *(const float4*)(tm_s);

    for (int r = 0; r < R; r++) {
        float w0 = (pa.x != 0) ? exp2f(fmaf(DLOG2E, pt.x, c0)) : 0.f;
        float w1 = (pa.y != 0) ? exp2f(fmaf(DLOG2E, pt.y, c0)) : 0.f;
        float w2 = (pa.z != 0) ? exp2f(fmaf(DLOG2E, pt.z, c0)) : 0.f;
        float w3 = (pa.w != 0) ? exp2f(fmaf(DLOG2E, pt.w, c0)) : 0.f;

        __syncthreads();   // previous round's tile fully consumed
        *(float4*)&tws[srow][scol] = make_float4(w0, w1, w2, w3);

        if (r + 1 < R) {   // prefetch next round during this round's compute
            pa = *(const int4*)(adj_s + (r + 1) * 128);
            pt = *(const float4*)(tm_s + (r + 1) * 128);
        }
        __syncthreads();   // tile r visible

        #pragma unroll
        for (int c4 = 0; c4 < 4; c4++) {
            int jl = c4 * 32 + q * 8;
            int jglob = r * 128 + c4 * 32;

            float4 w01 = *(const float4*)&tws[im][jl];
            float4 w23 = *(const float4*)&tws[im][jl + 4];
            float4 e0 = *(const float4*)(ed_p + jglob);
            float4 e1 = *(const float4*)(ed_p + jglob + 4);
            uint4  hv = *(const uint4*)(ht_p + jglob);

            float wv[8] = {w01.x, w01.y, w01.z, w01.w, w23.x, w23.y, w23.z, w23.w};
            float ev[8] = {e0.x, e0.y, e0.z, e0.w, e1.x, e1.y, e1.z, e1.w};

            union { unsigned short us[8]; short8 v; } af;
            #pragma unroll
            for (int k = 0; k < 8; k++) {
                float s0 = es_i + ev[k];
                float sc = fmaxf(s0, ALPHA * s0);     // leaky_relu
                float pv = exp2f(sc * wv[k]);         // w pre-scaled by log2e
                pv = (wv[k] > 0.f) ? pv : 0.f;        // masked -> 0
                __hip_bfloat16 hb = __float2bfloat16(pv);
                unsigned short ub;
                __builtin_memcpy(&ub, &hb, 2);
                af.us[k] = ub;
                lsum += bf2f(ub);   // denominator from the SAME rounded p
            }
            union { uint4 u; short8 v; } bf;
            bf.u = hv;
            acc = __builtin_amdgcn_mfma_f32_16x16x32_bf16(af.v, bf.v, acc, 0, 0, 0);
        }
    }

    // full row-sum l(i): partials live on lanes {i, i+16, i+32, i+48}
    lsum += __shfl_xor(lsum, 16);
    lsum += __shfl_xor(lsum, 32);
    float inv = 1.f / lsum;     // lane holds inv for row i = im

    // D layout: col = lane&15, row = q*4 + reg
    #pragma unroll
    for (int r = 0; r < 4; r++) {
        int row = q * 4 + r;
        float invr = __shfl(inv, row);          // lane 'row' holds l(row)
        float v = acc[r] * invr;
        v = (v > 0.f) ? v : expm1f(v);          // ELU (alpha=1)
        out[((size_t)(b * NN + i0 + row)) * (HH * HD) + w * HD + im] = v;
    }
}

extern "C" void kernel_launch(void* const* d_in, const int* in_sizes, int n_in,
                              void* d_out, int out_size, void* d_ws, size_t ws_size,
                              hipStream_t stream) {
    const float* x   = (const float*)d_in[0];
    const int*   adj = (const int*)d_in[1];
    const float* tm  = (const float*)d_in[2];
    const float* W   = (const float*)d_in[3];
    const float* a   = (const float*)d_in[4];
    float* out = (float*)d_out;

    float* wsf = (float*)d_ws;
    unsigned* ct = (unsigned*)wsf;                           // [0]
    float* Wt = wsf + 64;                                    // 16,384 floats
    float* es = Wt + INF * HH * HD;                          // 65,536
    float* ed = es + BN * HH * NN;                           // 65,536
    __hip_bfloat16* h_t = (__hip_bfloat16*)(ed + BN * HH * NN);  // 1,048,576 bf16

    k_prep <<<1, 256, 0, stream>>>(W, Wt, ct);
    k_setup<<<1024 + 4096, 256, 0, stream>>>(x, Wt, a, tm, ct, h_t, es, ed);
    k_attn <<<BN * (NN / 16), 512, 0, stream>>>(adj, tm, h_t, es, ed, ct, out);
}